// Round 9
// baseline (601.923 us; speedup 1.0000x reference)
//
#include <hip/hip_runtime.h>

#define T_LEN 2048
#define BSZ   256
#define NOBS  10
#define NCH   128          // chunks
#define CHL   16           // chunk length (NCH*CHL = T_LEN)
#define NHEAT 128          // heater blocks per kernel
#define HEAT_ITERS 40000   // ~130 us at 2.4 GHz (4 indep FMA chains)

// output offsets (floats)
#define OFF_XR   0
#define OFF_QMU  5242880
#define OFF_QCOV 7340032
#define OFF_PMU  15728640
#define OFF_PCOV 17825792

// workspace offsets (floats)
#define WS_K10   0
#define WS_PP10  20480
#define WS_L10   40960
#define WS_S4    61440
#define WS_TCONV 69632

// scratch inside x_recon output region (floats); fully consumed before kE
#define XR_KEYS  0         // 2048 x uint2
#define XR_MBUF  4096      // 2048 x 16
#define XR_EBUF  36864     // 2048 x 4
#define XR_VBUF  45056     // 128 x 16
#define XR_WBUF  47104     // 128 x 256 x 4
#define XR_ZMU   178176    // 2048 x 256 x 4
#define XR_KMID  2275328   // uint2
#define XR_HEAT  4500000   // heater sinks (dead; overwritten by kE)

__device__ __forceinline__ unsigned rotl32(unsigned v, int d) {
  return (v << d) | (v >> (32 - d));
}

// JAX threefry2x32: 20 rounds, key schedule every 4 rounds. (x0,x1) = counter in.
__device__ __forceinline__ void tf_block(unsigned k0, unsigned k1,
                                         unsigned& x0, unsigned& x1) {
  unsigned k2 = k0 ^ k1 ^ 0x1BD11BDAu;
  x0 += k0; x1 += k1;
#define TFR(r) { x0 += x1; x1 = rotl32(x1, r); x1 ^= x0; }
  TFR(13) TFR(15) TFR(26) TFR(6)
  x0 += k1; x1 += k2 + 1u;
  TFR(17) TFR(29) TFR(16) TFR(24)
  x0 += k2; x1 += k0 + 2u;
  TFR(13) TFR(15) TFR(26) TFR(6)
  x0 += k0; x1 += k1 + 3u;
  TFR(17) TFR(29) TFR(16) TFR(24)
  x0 += k1; x1 += k2 + 4u;
  TFR(13) TFR(15) TFR(26) TFR(6)
  x0 += k2; x1 += k0 + 5u;
#undef TFR
}

// Key-split chain step on the VALU. Bit-identical to tf_block(k0,k1, 0,0).
// v_alignbit = 1-op rotate; v_add3_u32 folds the two-add injections into one
// op / one dependency level. 72 ops, ~46 dep levels.
// %0=x0 %1=x1 %2=k2 %3=k0(in) %4=k1(in); nr = 32 - rot.
#define VR(nr) \
  "v_add_u32 %0, %0, %1\n\t" \
  "v_alignbit_b32 %1, %1, %1, " #nr "\n\t" \
  "v_xor_b32 %1, %1, %0\n\t"
__device__ __forceinline__ void chain_step_valu(unsigned& k0, unsigned& k1) {
  unsigned x0, x1, k2;
  asm("v_xor_b32 %2, %3, %4\n\t"
      "v_xor_b32 %2, 0x1BD11BDA, %2\n\t"
      // R1 (rot 13): x0 = k0+k1, x1 = rotl(k1,13)^x0
      "v_add_u32 %0, %3, %4\n\t"
      "v_alignbit_b32 %1, %4, %4, 19\n\t"
      "v_xor_b32 %1, %1, %0\n\t"
      VR(17) VR(6) VR(26)                 // R2-4: rot 15,26,6
      "v_add_u32 %0, %0, %4\n\t"          // I1: x0+=k1
      "v_add3_u32 %1, %1, %2, 1\n\t"      //     x1+=k2+1
      VR(15) VR(3) VR(16) VR(8)           // R5-8: rot 17,29,16,24
      "v_add_u32 %0, %0, %2\n\t"          // I2: x0+=k2
      "v_add3_u32 %1, %1, %3, 2\n\t"      //     x1+=k0+2
      VR(19) VR(17) VR(6) VR(26)          // R9-12: rot 13,15,26,6
      "v_add_u32 %0, %0, %3\n\t"          // I3: x0+=k0
      "v_add3_u32 %1, %1, %4, 3\n\t"      //     x1+=k1+3
      VR(15) VR(3) VR(16) VR(8)           // R13-16
      "v_add_u32 %0, %0, %4\n\t"          // I4: x0+=k1
      "v_add3_u32 %1, %1, %2, 4\n\t"      //     x1+=k2+4
      VR(19) VR(17) VR(6) VR(26)          // R17-20
      "v_add_u32 %0, %0, %2\n\t"          // I5: x0+=k2
      "v_add3_u32 %1, %1, %3, 5"          //     x1+=k0+5
      : "=&v"(x0), "=&v"(x1), "=&v"(k2)
      : "v"(k0), "v"(k1));
  k0 = x0; k1 = x1;
}
#undef VR

__device__ __forceinline__ bool valu_selfcheck(unsigned k0, unsigned k1) {
  unsigned a0 = k0, a1 = k1, c0 = k0, c1 = k1;
  bool ok = true;
  for (int i = 0; i < 4; ++i) {
    chain_step_valu(a0, a1);
    unsigned t0 = 0u, t1 = 0u;
    tf_block(c0, c1, t0, t1);
    c0 = t0; c1 = t1;
    ok = ok && (a0 == c0) && (a1 == c1);
  }
  return ok;
}

// Fixed-count ILP-4 FMA heater: keeps DVFS clocks up while the serial chain
// runs. Deterministic; sink is dead scratch overwritten by kE.
__device__ __forceinline__ void heater_body(float* sink, int idx) {
  float a = 1.0f, b = 1.0001f, c = 0.9999f, d = 1.00005f;
  for (int i = 0; i < HEAT_ITERS; ++i) {
    a = fmaf(a, 1.0000001f, 1e-9f);
    b = fmaf(b, 0.9999999f, 1e-9f);
    c = fmaf(c, 1.0000002f, 1e-9f);
    d = fmaf(d, 0.9999998f, 1e-9f);
  }
  if (threadIdx.x == 0) sink[idx] = a + b + c + d;
}

// XLA ErfInv32 (Giles polynomial), matches lax.erf_inv f32 lowering.
__device__ __forceinline__ float erfinv_xla(float x) {
  float w = -log1pf(-x * x);
  float p;
  if (w < 5.0f) {
    w = w - 2.5f;
    p = 2.81022636e-08f;
    p = fmaf(p, w, 3.43273939e-07f);
    p = fmaf(p, w, -3.5233877e-06f);
    p = fmaf(p, w, -4.39150654e-06f);
    p = fmaf(p, w, 0.00021858087f);
    p = fmaf(p, w, -0.00125372503f);
    p = fmaf(p, w, -0.00417768164f);
    p = fmaf(p, w, 0.246640727f);
    p = fmaf(p, w, 1.50140941f);
  } else {
    w = sqrtf(w) - 3.0f;
    p = -0.000200214257f;
    p = fmaf(p, w, 0.000100950558f);
    p = fmaf(p, w, 0.00134934322f);
    p = fmaf(p, w, -0.00367342844f);
    p = fmaf(p, w, 0.00573950773f);
    p = fmaf(p, w, -0.0076224613f);
    p = fmaf(p, w, 0.00943887047f);
    p = fmaf(p, w, 1.00167406f);
    p = fmaf(p, w, 2.83297682f);
  }
  return p * x;
}

// Kernel A (grid 2050+NHEAT, no cross-block sync):
//   blk 0         : threefry chain t in [0,1024) -> keybuf; kmid -> XR_KMID
//   blk 1         : Riccati (tol cutoff) -> K10/Pp10/L10/tc (ws) + Mbuf/ebuf (xr)
//   blk 2..2049   : encoder z_mu (t = blk-2) -> XR_ZMU
//   blk 2050+     : heater
__global__ void __launch_bounds__(256) svae_kA(
    const float* __restrict__ x,
    const float* __restrict__ ew1, const float* __restrict__ eb1,
    const float* __restrict__ ewx, const float* __restrict__ ebx,
    const float* __restrict__ A, const float* __restrict__ bvec,
    const float* __restrict__ Q, const int* __restrict__ seedp,
    float* __restrict__ xr, float* __restrict__ wsf) {
  int blk = blockIdx.x;

  if (blk == 0) {
    if (threadIdx.x != 0) return;
    unsigned long long us = (unsigned long long)(long long)(*seedp);
    unsigned k0 = (unsigned)(us >> 32), k1 = (unsigned)(us & 0xFFFFFFFFull);
    uint2* keys = (uint2*)(xr + XR_KEYS);
    bool ok = valu_selfcheck(k0, k1);
    __builtin_amdgcn_s_setprio(1);
    if (ok) {
#pragma unroll 4
      for (int t = 0; t < T_LEN/2; ++t) {
        keys[t] = make_uint2(k0, k1);
        chain_step_valu(k0, k1);
      }
    } else {
      for (int t = 0; t < T_LEN/2; ++t) {
        keys[t] = make_uint2(k0, k1);
        unsigned t0 = 0u, t1 = 0u;
        tf_block(k0, k1, t0, t1);
        k0 = t0; k1 = t1;
      }
    }
    __builtin_amdgcn_s_setprio(0);
    *(uint2*)(xr + XR_KMID) = make_uint2(k0, k1);
    return;
  }

  if (blk == 1) {
    // ---------------- Riccati chain (batch-independent) ----------------
    if (threadIdx.x != 0) return;
    float Am[16], Qm[16];
#pragma unroll
    for (int i = 0; i < 16; ++i) Am[i] = A[i];
    float bv[4];
#pragma unroll
    for (int i = 0; i < 4; ++i) bv[i] = bvec[i];
#pragma unroll
    for (int i = 0; i < 4; ++i)
#pragma unroll
      for (int j = 0; j < 4; ++j) {
        float s = 0.f;
#pragma unroll
        for (int k = 0; k < 4; ++k) s += Q[k*4+i] * Q[k*4+j];
        Qm[i*4+j] = s;
      }
    float P[16] = {1,0,0,0, 0,1,0,0, 0,0,1,0, 0,0,0,1};
    unsigned pb1[10], pb2[10];
    float pk[10];
#pragma unroll
    for (int i = 0; i < 10; ++i) { pb1[i] = 0xDEADBEEFu; pb2[i] = 0xFEEDFACEu; pk[i] = 1e30f; }
    int tc = T_LEN - 1;
    int streak = 0;
    float* K10  = wsf + WS_K10;
    float* Pp10 = wsf + WS_PP10;
    float* L10  = wsf + WS_L10;
    float* Mb   = xr + XR_MBUF;
    float* Eb   = xr + XR_EBUF;
    for (int t = 0; t < T_LEN; ++t) {
      float M[16];
#pragma unroll
      for (int i = 0; i < 4; ++i)
#pragma unroll
        for (int l = 0; l < 4; ++l) {
          float s = Am[i*4+0]*P[0*4+l];
          s += Am[i*4+1]*P[1*4+l];
          s += Am[i*4+2]*P[2*4+l];
          s += Am[i*4+3]*P[3*4+l];
          M[i*4+l] = s;
        }
      float Pp[16];
#pragma unroll
      for (int i = 0; i < 4; ++i)
#pragma unroll
        for (int j = 0; j < 4; ++j) {
          if (j > i) continue;
          float s = Qm[i*4+j];
          s += M[i*4+0]*Am[j*4+0];
          s += M[i*4+1]*Am[j*4+1];
          s += M[i*4+2]*Am[j*4+2];
          s += M[i*4+3]*Am[j*4+3];
          Pp[i*4+j] = s; Pp[j*4+i] = s;
        }
      float l00 = sqrtf(Pp[0]+1.f); float i00 = 1.f/l00;
      float l10 = Pp[4]*i00, l20 = Pp[8]*i00, l30 = Pp[12]*i00;
      float l11 = sqrtf(Pp[5]+1.f - l10*l10); float i11 = 1.f/l11;
      float l21 = (Pp[9]  - l20*l10)*i11;
      float l31 = (Pp[13] - l30*l10)*i11;
      float l22 = sqrtf(Pp[10]+1.f - l20*l20 - l21*l21); float i22 = 1.f/l22;
      float l32 = (Pp[14] - l30*l20 - l31*l21)*i22;
      float l33 = sqrtf(Pp[15]+1.f - l30*l30 - l31*l31 - l32*l32); float i33 = 1.f/l33;
      float Li10 = -(l10*i00)*i11;
      float Li20 = -(l20*i00 + l21*Li10)*i22;
      float Li21 = -(l21*i11)*i22;
      float Li30 = -(l30*i00 + l31*Li10 + l32*Li20)*i33;
      float Li31 = -(l31*i11 + l32*Li21)*i33;
      float Li32 = -(l32*i22)*i33;
      float Si00 = i00*i00 + Li10*Li10 + Li20*Li20 + Li30*Li30;
      float Si10 = Li10*i11 + Li20*Li21 + Li30*Li31;
      float Si11 = i11*i11 + Li21*Li21 + Li31*Li31;
      float Si20 = Li20*i22 + Li30*Li32;
      float Si21 = Li21*i22 + Li31*Li32;
      float Si22 = i22*i22 + Li32*Li32;
      float Si30 = Li30*i33;
      float Si31 = Li31*i33;
      float Si32 = Li32*i33;
      float Si33 = i33*i33;
      float Kv[10];
      Kv[0] = 1.f - Si00; Kv[1] = -Si10; Kv[2] = 1.f - Si11;
      Kv[3] = -Si20; Kv[4] = -Si21; Kv[5] = 1.f - Si22;
      Kv[6] = -Si30; Kv[7] = -Si31; Kv[8] = -Si32; Kv[9] = 1.f - Si33;
      float c00 = sqrtf(Kv[0]+1e-3f); float j00 = 1.f/c00;
      float c10 = Kv[1]*j00, c20 = Kv[3]*j00, c30 = Kv[6]*j00;
      float c11 = sqrtf(Kv[2]+1e-3f - c10*c10); float j11 = 1.f/c11;
      float c21 = (Kv[4] - c20*c10)*j11;
      float c31 = (Kv[7] - c30*c10)*j11;
      float c22 = sqrtf(Kv[5]+1e-3f - c20*c20 - c21*c21); float j22 = 1.f/c22;
      float c32 = (Kv[8] - c30*c20 - c31*c21)*j22;
      float c33 = sqrtf(Kv[9]+1e-3f - c30*c30 - c31*c31 - c32*c32);
      {
        float* kw = K10 + t*10;
#pragma unroll
        for (int i = 0; i < 10; ++i) kw[i] = Kv[i];
        float* pw = Pp10 + t*10;
        pw[0]=Pp[0]; pw[1]=Pp[4]; pw[2]=Pp[5]; pw[3]=Pp[8]; pw[4]=Pp[9];
        pw[5]=Pp[10]; pw[6]=Pp[12]; pw[7]=Pp[13]; pw[8]=Pp[14]; pw[9]=Pp[15];
        float* lw = L10 + t*10;
        lw[0]=c00; lw[1]=c10; lw[2]=c11; lw[3]=c20; lw[4]=c21;
        lw[5]=c22; lw[6]=c30; lw[7]=c31; lw[8]=c32; lw[9]=c33;
        float Kf[16] = {Kv[0],Kv[1],Kv[3],Kv[6],
                        Kv[1],Kv[2],Kv[4],Kv[7],
                        Kv[3],Kv[4],Kv[5],Kv[8],
                        Kv[6],Kv[7],Kv[8],Kv[9]};
        float* mw = Mb + t*16;
        float* ew = Eb + t*4;
#pragma unroll
        for (int j = 0; j < 4; ++j) {
          float g0 = (j==0?1.f:0.f) - Kf[j*4+0];
          float g1 = (j==1?1.f:0.f) - Kf[j*4+1];
          float g2 = (j==2?1.f:0.f) - Kf[j*4+2];
          float g3 = (j==3?1.f:0.f) - Kf[j*4+3];
#pragma unroll
          for (int i = 0; i < 4; ++i)
            mw[j*4+i] = g0*Am[i*4+0] + g1*Am[i*4+1] + g2*Am[i*4+2] + g3*Am[i*4+3];
          ew[j] = g0*bv[0] + g1*bv[1] + g2*bv[2] + g3*bv[3];
        }
      }
      unsigned nb[10];
#pragma unroll
      for (int i = 0; i < 10; ++i) nb[i] = __float_as_uint(Kv[i]);
      bool eq1 = true, eq2 = true;
      float dmax = 0.f;
#pragma unroll
      for (int i = 0; i < 10; ++i) {
        eq1 &= (nb[i]==pb1[i]); eq2 &= (nb[i]==pb2[i]);
        dmax = fmaxf(dmax, fabsf(Kv[i] - pk[i]));
      }
      streak = (dmax <= 1e-6f) ? (streak + 1) : 0;
      if (eq1 || eq2 || streak >= 2) { tc = t; break; }
#pragma unroll
      for (int i = 0; i < 10; ++i) { pb2[i] = pb1[i]; pb1[i] = nb[i]; pk[i] = Kv[i]; }
      P[0]=Kv[0];  P[1]=Kv[1];  P[2]=Kv[3];  P[3]=Kv[6];
      P[4]=Kv[1];  P[5]=Kv[2];  P[6]=Kv[4];  P[7]=Kv[7];
      P[8]=Kv[3];  P[9]=Kv[4];  P[10]=Kv[5]; P[11]=Kv[8];
      P[12]=Kv[6]; P[13]=Kv[7]; P[14]=Kv[8]; P[15]=Kv[9];
    }
    *((int*)(wsf + WS_TCONV)) = tc;
    return;
  }

  if (blk < 2 + T_LEN) {
    // ---------------- encoder: block = one t, 256 b's ----------------
    int t = blk - 2;
    int b = threadIdx.x;
    float* zmu = xr + XR_ZMU;
    const float* xp = x + ((size_t)b * T_LEN + t) * NOBS;
    float xv[10];
#pragma unroll
    for (int i = 0; i < 10; ++i) xv[i] = xp[i];
    float h[6];
#pragma unroll
    for (int k = 0; k < 6; ++k) {
      float s = eb1[k];
#pragma unroll
      for (int i = 0; i < 10; ++i) s += xv[i]*ew1[i*6+k];
      h[k] = fmaxf(s, 0.f);
    }
    float z[4];
#pragma unroll
    for (int j = 0; j < 4; ++j) {
      float s = ebx[j];
#pragma unroll
      for (int k = 0; k < 6; ++k) s += h[k]*ewx[k*4+j];
      z[j] = s;
    }
    *reinterpret_cast<float4*>(zmu + (size_t)(t*BSZ + b)*4) =
        make_float4(z[0], z[1], z[2], z[3]);
    return;
  }

  // ---------------- heater ----------------
  heater_body(xr + XR_HEAT, blk - (2 + T_LEN));
}

// Kernel B (grid 2177+NHEAT):
//   blk 0          : threefry chain t in [1024,2048) from kmid -> keybuf
//   blk 1..128     : phaseA chunk fold (c = blk-1) -> Vbuf, wbuf
//   blk 129..2176  : cov broadcast (t = blk-129) -> q_cov, p_cov
//   blk 2177+      : heater
__global__ void __launch_bounds__(256) svae_kB(
    const int* __restrict__ seedp,
    float* __restrict__ xr, const float* __restrict__ wsc,
    float* __restrict__ q_cov, float* __restrict__ p_cov) {
  int blk = blockIdx.x;
  if (blk == 0) {
    if (threadIdx.x != 0) return;
    unsigned long long us = (unsigned long long)(long long)(*seedp);
    bool ok = valu_selfcheck((unsigned)(us >> 32), (unsigned)(us & 0xFFFFFFFFull));
    uint2 km = *(const uint2*)(xr + XR_KMID);
    unsigned k0 = km.x, k1 = km.y;
    uint2* keys = (uint2*)(xr + XR_KEYS);
    __builtin_amdgcn_s_setprio(1);
    if (ok) {
#pragma unroll 4
      for (int t = T_LEN/2; t < T_LEN; ++t) {
        keys[t] = make_uint2(k0, k1);
        chain_step_valu(k0, k1);
      }
    } else {
      for (int t = T_LEN/2; t < T_LEN; ++t) {
        keys[t] = make_uint2(k0, k1);
        unsigned t0 = 0u, t1 = 0u;
        tf_block(k0, k1, t0, t1);
        k0 = t0; k1 = t1;
      }
    }
    __builtin_amdgcn_s_setprio(0);
    return;
  }
  if (blk <= NCH) {
    // ---------------- phaseA: chunk-local affine fold ----------------
    int c = blk - 1;
    int b = threadIdx.x;
    const float* Mb  = xr + XR_MBUF;
    const float* Eb  = xr + XR_EBUF;
    const float* K10 = wsc + WS_K10;
    const float* zmu = xr + XR_ZMU;
    int tc = *((const int*)(wsc + WS_TCONV));
    float V[16] = {1,0,0,0, 0,1,0,0, 0,0,1,0, 0,0,0,1};
    float w0 = 0.f, w1 = 0.f, w2 = 0.f, w3 = 0.f;
#pragma unroll
    for (int k = 0; k < CHL; ++k) {
      int t = c*CHL + k;
      int tt = (t < tc) ? t : tc;
      const float* mp = Mb + (size_t)tt*16;
      const float* ep = Eb + (size_t)tt*4;
      const float* kp = K10 + (size_t)tt*10;
      float4 z = *reinterpret_cast<const float4*>(zmu + (size_t)(t*BSZ + b)*4);
      float k0=kp[0],k1=kp[1],k2=kp[2],k3=kp[3],k4=kp[4];
      float k5=kp[5],k6=kp[6],k7=kp[7],k8=kp[8],k9=kp[9];
      float c0 = ep[0] + k0*z.x + k1*z.y + k3*z.z + k6*z.w;
      float c1 = ep[1] + k1*z.x + k2*z.y + k4*z.z + k7*z.w;
      float c2 = ep[2] + k3*z.x + k4*z.y + k5*z.z + k8*z.w;
      float c3 = ep[3] + k6*z.x + k7*z.y + k8*z.z + k9*z.w;
      float m[16];
#pragma unroll
      for (int i = 0; i < 16; ++i) m[i] = mp[i];
      float nw0 = c0 + m[0]*w0 + m[1]*w1 + m[2]*w2 + m[3]*w3;
      float nw1 = c1 + m[4]*w0 + m[5]*w1 + m[6]*w2 + m[7]*w3;
      float nw2 = c2 + m[8]*w0 + m[9]*w1 + m[10]*w2 + m[11]*w3;
      float nw3 = c3 + m[12]*w0 + m[13]*w1 + m[14]*w2 + m[15]*w3;
      w0 = nw0; w1 = nw1; w2 = nw2; w3 = nw3;
      float nV[16];
#pragma unroll
      for (int j = 0; j < 4; ++j)
#pragma unroll
        for (int i = 0; i < 4; ++i)
          nV[j*4+i] = m[j*4+0]*V[0*4+i] + m[j*4+1]*V[1*4+i]
                    + m[j*4+2]*V[2*4+i] + m[j*4+3]*V[3*4+i];
#pragma unroll
      for (int i = 0; i < 16; ++i) V[i] = nV[i];
    }
    float* wb = xr + XR_WBUF;
    *reinterpret_cast<float4*>(wb + (size_t)(c*BSZ + b)*4) =
        make_float4(w0, w1, w2, w3);
    if (threadIdx.x == 0) {
      float* vb = xr + XR_VBUF + (size_t)c*16;
#pragma unroll
      for (int i = 0; i < 16; ++i) vb[i] = V[i];
    }
    return;
  }
  if (blk <= NCH + T_LEN) {
    // ---------------- cov broadcast ----------------
    int t = blk - (NCH + 1);
    int b = threadIdx.x;
    int tc = *((const int*)(wsc + WS_TCONV));
    int tt = (t < tc) ? t : tc;
    const float* kp = wsc + WS_K10 + (size_t)tt*10;
    const float* pp = wsc + WS_PP10 + (size_t)tt*10;
    float kv[10], pv[10];
#pragma unroll
    for (int i = 0; i < 10; ++i) { kv[i] = kp[i]; pv[i] = pp[i]; }
    float* qc = q_cov + (size_t)(t*BSZ + b)*16;
    float* pc = p_cov + (size_t)(t*BSZ + b)*16;
    const int mp[16] = {0,1,3,6, 1,2,4,7, 3,4,5,8, 6,7,8,9};
#pragma unroll
    for (int r = 0; r < 4; ++r) {
      *reinterpret_cast<float4*>(qc + r*4) = make_float4(
          kv[mp[r*4]], kv[mp[r*4+1]], kv[mp[r*4+2]], kv[mp[r*4+3]]);
      *reinterpret_cast<float4*>(pc + r*4) = make_float4(
          pv[mp[r*4]], pv[mp[r*4+1]], pv[mp[r*4+2]], pv[mp[r*4+3]]);
    }
    return;
  }
  // ---------------- heater ----------------
  heater_body(xr + XR_HEAT + NHEAT, blk - (NCH + T_LEN + 1));
}

// Kernel D (grid 136):
//   blk 0..127   : chunk c -- redundant in-register boundary scan over chunks
//                  < c (V,w from phaseA), then exact 16-step recompute -> q_mu,p_mu
//   blk 128..135 : u-gen (t = (blk-128)*256 + tid) -> s4
__global__ void __launch_bounds__(256) svae_kD(
    const float* __restrict__ A, const float* __restrict__ bvec,
    const float* __restrict__ xr, const float* __restrict__ wsc,
    float* __restrict__ wsf,
    float* __restrict__ q_mu, float* __restrict__ p_mu) {
  int blk = blockIdx.x;
  if (blk < NCH) {
    int c = blk;
    int b = threadIdx.x;
    const float* vb = xr + XR_VBUF;
    const float* wb = xr + XR_WBUF;
    float mu0 = 0.f, mu1 = 0.f, mu2 = 0.f, mu3 = 0.f;
    for (int cc = 0; cc < c; ++cc) {
      const float* V = vb + (size_t)cc*16;
      float4 wv = *reinterpret_cast<const float4*>(wb + (size_t)(cc*BSZ + b)*4);
      float n0 = wv.x + V[0]*mu0  + V[1]*mu1  + V[2]*mu2  + V[3]*mu3;
      float n1 = wv.y + V[4]*mu0  + V[5]*mu1  + V[6]*mu2  + V[7]*mu3;
      float n2 = wv.z + V[8]*mu0  + V[9]*mu1  + V[10]*mu2 + V[11]*mu3;
      float n3 = wv.w + V[12]*mu0 + V[13]*mu1 + V[14]*mu2 + V[15]*mu3;
      mu0 = n0; mu1 = n1; mu2 = n2; mu3 = n3;
    }
    const float* K10 = wsc + WS_K10;
    const float* zmu = xr + XR_ZMU;
    int tc = *((const int*)(wsc + WS_TCONV));
    float Am[16];
#pragma unroll
    for (int i = 0; i < 16; ++i) Am[i] = A[i];
    float b0 = bvec[0], b1 = bvec[1], b2 = bvec[2], b3 = bvec[3];
#pragma unroll
    for (int k = 0; k < CHL; ++k) {
      int t = c*CHL + k;
      int tt = (t < tc) ? t : tc;
      const float* kp = K10 + (size_t)tt*10;
      float kc0=kp[0],kc1=kp[1],kc2=kp[2],kc3=kp[3],kc4=kp[4];
      float kc5=kp[5],kc6=kp[6],kc7=kp[7],kc8=kp[8],kc9=kp[9];
      float4 zv = *reinterpret_cast<const float4*>(zmu + (size_t)(t*BSZ + b)*4);
      float mp0 = b0 + mu0*Am[0] + mu1*Am[4] + mu2*Am[8]  + mu3*Am[12];
      float mp1 = b1 + mu0*Am[1] + mu1*Am[5] + mu2*Am[9]  + mu3*Am[13];
      float mp2 = b2 + mu0*Am[2] + mu1*Am[6] + mu2*Am[10] + mu3*Am[14];
      float mp3 = b3 + mu0*Am[3] + mu1*Am[7] + mu2*Am[11] + mu3*Am[15];
      float r0 = zv.x - mp0, r1 = zv.y - mp1, r2 = zv.z - mp2, r3 = zv.w - mp3;
      mu0 = mp0 + kc0*r0 + kc1*r1 + kc3*r2 + kc6*r3;
      mu1 = mp1 + kc1*r0 + kc2*r1 + kc4*r2 + kc7*r3;
      mu2 = mp2 + kc3*r0 + kc4*r1 + kc5*r2 + kc8*r3;
      mu3 = mp3 + kc6*r0 + kc7*r1 + kc8*r2 + kc9*r3;
      *reinterpret_cast<float4*>(p_mu + (size_t)(t*BSZ + b)*4) =
          make_float4(mp0, mp1, mp2, mp3);
      *reinterpret_cast<float4*>(q_mu + (size_t)(t*BSZ + b)*4) =
          make_float4(mu0, mu1, mu2, mu3);
    }
    return;
  }
  // ---------------- u-gen: 4 normals per t, s_t = u^T L ----------------
  {
    int t = (blk - NCH) * 256 + threadIdx.x;
    const uint2* keys = (const uint2*)(xr + XR_KEYS);
    const float* L10 = wsc + WS_L10;
    int tc = *((const int*)(wsc + WS_TCONV));
    const float LO = __uint_as_float(0xBF7FFFFFu);   // nextafter(-1,0)
    float* s4 = wsf + WS_S4;
    uint2 kk = keys[t];
    unsigned s0 = 0u, s1 = 1u;            // skey: ctr (0,1)
    tf_block(kk.x, kk.y, s0, s1);
    float n[4];
#pragma unroll
    for (int i = 0; i < 4; ++i) {
      unsigned y0 = 0u, y1 = (unsigned)i;  // bits: ctr (0,i), fold xor
      tf_block(s0, s1, y0, y1);
      unsigned bits = y0 ^ y1;
      float f = __uint_as_float((bits >> 9) | 0x3F800000u) - 1.0f;
      float v = fmaxf(LO, f * 2.0f + LO);
      n[i] = 1.41421356237309505f * erfinv_xla(v);
    }
    const float* Lp = L10 + (size_t)((t < tc) ? t : tc) * 10;
    float s_0 = n[0]*Lp[0] + n[1]*Lp[1] + n[2]*Lp[3] + n[3]*Lp[6];
    float s_1 = n[1]*Lp[2] + n[2]*Lp[4] + n[3]*Lp[7];
    float s_2 = n[2]*Lp[5] + n[3]*Lp[8];
    float s_3 = n[3]*Lp[9];
    *reinterpret_cast<float4*>(s4 + 4*t) = make_float4(s_0, s_1, s_2, s_3);
  }
}

// Kernel E (grid 256): decoder, block = batch b, threads over t (contiguous
// 40B stores per lane). Overwrites all xr scratch -- must be LAST.
__global__ void __launch_bounds__(256) svae_kE(
    const float* __restrict__ q_mu, const float* __restrict__ wsc,
    const float* __restrict__ dw1, const float* __restrict__ db1,
    const float* __restrict__ dw2, const float* __restrict__ db2,
    float* __restrict__ xr) {
  int b = blockIdx.x;
  const float* s4 = wsc + WS_S4;
  float w1[24], bb1[6], w2[60], bb2[10];
#pragma unroll
  for (int i = 0; i < 24; ++i) w1[i] = dw1[i];
#pragma unroll
  for (int i = 0; i < 6; ++i) bb1[i] = db1[i];
#pragma unroll
  for (int i = 0; i < 60; ++i) w2[i] = dw2[i];
#pragma unroll
  for (int i = 0; i < 10; ++i) bb2[i] = db2[i];
#pragma unroll
  for (int i = 0; i < T_LEN / 256; ++i) {
    int t = i * 256 + threadIdx.x;
    float4 mu = *reinterpret_cast<const float4*>(q_mu + (size_t)(t*BSZ + b)*4);
    float4 sv = *reinterpret_cast<const float4*>(s4 + 4*t);
    float z0 = mu.x + sv.x, z1 = mu.y + sv.y, z2 = mu.z + sv.z, z3 = mu.w + sv.w;
    float hd[6];
#pragma unroll
    for (int k = 0; k < 6; ++k) {
      float v = bb1[k] + z0*w1[k] + z1*w1[6+k] + z2*w1[12+k] + z3*w1[18+k];
      hd[k] = fmaxf(v, 0.f);
    }
    float o[10];
#pragma unroll
    for (int oo = 0; oo < 10; ++oo) {
      float v = bb2[oo];
#pragma unroll
      for (int k = 0; k < 6; ++k) v += hd[k]*w2[k*10+oo];
      o[oo] = v;
    }
    float* xo = xr + ((size_t)b * T_LEN + t) * 10;
#pragma unroll
    for (int p2 = 0; p2 < 5; ++p2)
      *reinterpret_cast<float2*>(xo + p2*2) = make_float2(o[p2*2], o[p2*2+1]);
  }
}

extern "C" void kernel_launch(void* const* d_in, const int* in_sizes, int n_in,
                              void* d_out, int out_size, void* d_ws, size_t ws_size,
                              hipStream_t stream) {
  const float* x   = (const float*)d_in[0];
  const float* ew1 = (const float*)d_in[1];
  const float* eb1 = (const float*)d_in[2];
  const float* ewx = (const float*)d_in[3];
  const float* ebx = (const float*)d_in[4];
  // d_in[5], d_in[6]: enc_wl/enc_bl -- unused by the filter
  const float* dw1 = (const float*)d_in[7];
  const float* db1 = (const float*)d_in[8];
  const float* dw2 = (const float*)d_in[9];
  const float* db2 = (const float*)d_in[10];
  const float* Ain = (const float*)d_in[11];
  const float* bin = (const float*)d_in[12];
  const float* Qin = (const float*)d_in[13];
  const int* seed  = (const int*)d_in[14];

  float* out   = (float*)d_out;
  float* xr    = out + OFF_XR;     // also hosts all large scratch until kE
  float* q_mu  = out + OFF_QMU;
  float* q_cov = out + OFF_QCOV;
  float* p_mu  = out + OFF_PMU;
  float* p_cov = out + OFF_PCOV;
  float* wsf   = (float*)d_ws;

  svae_kA<<<T_LEN + 2 + NHEAT, 256, 0, stream>>>(x, ew1, eb1, ewx, ebx, Ain,
                                                 bin, Qin, seed, xr, wsf);
  svae_kB<<<1 + NCH + T_LEN + NHEAT, 256, 0, stream>>>(seed, xr, wsf,
                                                       q_cov, p_cov);
  svae_kD<<<NCH + 8, 256, 0, stream>>>(Ain, bin, xr, wsf, wsf, q_mu, p_mu);
  svae_kE<<<BSZ, 256, 0, stream>>>(q_mu, wsf, dw1, db1, dw2, db2, xr);
}

// Round 10
// 386.192 us; speedup vs baseline: 1.5586x; 1.5586x over previous
//
#include <hip/hip_runtime.h>

#define T_LEN 2048
#define BSZ   256
#define NOBS  10
#define NCH   128          // chunks
#define CHL   16           // chunk length (NCH*CHL = T_LEN)

// output offsets (floats)
#define OFF_XR   0
#define OFF_QMU  5242880
#define OFF_QCOV 7340032
#define OFF_PMU  15728640
#define OFF_PCOV 17825792

// workspace offsets (floats)
#define WS_K10   0
#define WS_PP10  20480
#define WS_L10   40960
#define WS_S4    61440
#define WS_TCONV 69632

// scratch inside x_recon output region (floats); fully consumed before kE
#define XR_KEYS  0         // 2048 x uint2
#define XR_MBUF  4096      // 2048 x 16
#define XR_EBUF  36864     // 2048 x 4
#define XR_VBUF  45056     // 128 x 16
#define XR_WBUF  47104     // 128 x 256 x 4
#define XR_ZMU   178176    // 2048 x 256 x 4
#define XR_KMID  2275328   // uint2

__device__ __forceinline__ unsigned rotl32(unsigned v, int d) {
  return (v << d) | (v >> (32 - d));
}

// JAX threefry2x32: 20 rounds, key schedule every 4 rounds. (x0,x1) = counter in.
__device__ __forceinline__ void tf_block(unsigned k0, unsigned k1,
                                         unsigned& x0, unsigned& x1) {
  unsigned k2 = k0 ^ k1 ^ 0x1BD11BDAu;
  x0 += k0; x1 += k1;
#define TFR(r) { x0 += x1; x1 = rotl32(x1, r); x1 ^= x0; }
  TFR(13) TFR(15) TFR(26) TFR(6)
  x0 += k1; x1 += k2 + 1u;
  TFR(17) TFR(29) TFR(16) TFR(24)
  x0 += k2; x1 += k0 + 2u;
  TFR(13) TFR(15) TFR(26) TFR(6)
  x0 += k0; x1 += k1 + 3u;
  TFR(17) TFR(29) TFR(16) TFR(24)
  x0 += k1; x1 += k2 + 4u;
  TFR(13) TFR(15) TFR(26) TFR(6)
  x0 += k2; x1 += k0 + 5u;
#undef TFR
}

// Key-split chain step on the VALU. Bit-identical to tf_block(k0,k1, 0,0).
// v_alignbit = 1-op rotate; v_add3_u32 folds the two-add injections into one
// op / one dependency level. ~46 dependency levels -- the serial floor.
// %0=x0 %1=x1 %2=k2 %3=k0(in) %4=k1(in); nr = 32 - rot.
#define VR(nr) \
  "v_add_u32 %0, %0, %1\n\t" \
  "v_alignbit_b32 %1, %1, %1, " #nr "\n\t" \
  "v_xor_b32 %1, %1, %0\n\t"
__device__ __forceinline__ void chain_step_valu(unsigned& k0, unsigned& k1) {
  unsigned x0, x1, k2;
  asm("v_xor_b32 %2, %3, %4\n\t"
      "v_xor_b32 %2, 0x1BD11BDA, %2\n\t"
      // R1 (rot 13): x0 = k0+k1, x1 = rotl(k1,13)^x0
      "v_add_u32 %0, %3, %4\n\t"
      "v_alignbit_b32 %1, %4, %4, 19\n\t"
      "v_xor_b32 %1, %1, %0\n\t"
      VR(17) VR(6) VR(26)                 // R2-4: rot 15,26,6
      "v_add_u32 %0, %0, %4\n\t"          // I1: x0+=k1
      "v_add3_u32 %1, %1, %2, 1\n\t"      //     x1+=k2+1
      VR(15) VR(3) VR(16) VR(8)           // R5-8: rot 17,29,16,24
      "v_add_u32 %0, %0, %2\n\t"          // I2: x0+=k2
      "v_add3_u32 %1, %1, %3, 2\n\t"      //     x1+=k0+2
      VR(19) VR(17) VR(6) VR(26)          // R9-12: rot 13,15,26,6
      "v_add_u32 %0, %0, %3\n\t"          // I3: x0+=k0
      "v_add3_u32 %1, %1, %4, 3\n\t"      //     x1+=k1+3
      VR(15) VR(3) VR(16) VR(8)           // R13-16
      "v_add_u32 %0, %0, %4\n\t"          // I4: x0+=k1
      "v_add3_u32 %1, %1, %2, 4\n\t"      //     x1+=k2+4
      VR(19) VR(17) VR(6) VR(26)          // R17-20
      "v_add_u32 %0, %0, %2\n\t"          // I5: x0+=k2
      "v_add3_u32 %1, %1, %3, 5"          //     x1+=k0+5
      : "=&v"(x0), "=&v"(x1), "=&v"(k2)
      : "v"(k0), "v"(k1));
  k0 = x0; k1 = x1;
}
#undef VR

__device__ __forceinline__ bool valu_selfcheck(unsigned k0, unsigned k1) {
  unsigned a0 = k0, a1 = k1, c0 = k0, c1 = k1;
  bool ok = true;
  for (int i = 0; i < 4; ++i) {
    chain_step_valu(a0, a1);
    unsigned t0 = 0u, t1 = 0u;
    tf_block(c0, c1, t0, t1);
    c0 = t0; c1 = t1;
    ok = ok && (a0 == c0) && (a1 == c1);
  }
  return ok;
}

// XLA ErfInv32 (Giles polynomial), matches lax.erf_inv f32 lowering.
__device__ __forceinline__ float erfinv_xla(float x) {
  float w = -log1pf(-x * x);
  float p;
  if (w < 5.0f) {
    w = w - 2.5f;
    p = 2.81022636e-08f;
    p = fmaf(p, w, 3.43273939e-07f);
    p = fmaf(p, w, -3.5233877e-06f);
    p = fmaf(p, w, -4.39150654e-06f);
    p = fmaf(p, w, 0.00021858087f);
    p = fmaf(p, w, -0.00125372503f);
    p = fmaf(p, w, -0.00417768164f);
    p = fmaf(p, w, 0.246640727f);
    p = fmaf(p, w, 1.50140941f);
  } else {
    w = sqrtf(w) - 3.0f;
    p = -0.000200214257f;
    p = fmaf(p, w, 0.000100950558f);
    p = fmaf(p, w, 0.00134934322f);
    p = fmaf(p, w, -0.00367342844f);
    p = fmaf(p, w, 0.00573950773f);
    p = fmaf(p, w, -0.0076224613f);
    p = fmaf(p, w, 0.00943887047f);
    p = fmaf(p, w, 1.00167406f);
    p = fmaf(p, w, 2.83297682f);
  }
  return p * x;
}

// Kernel A (grid 2050, no cross-block sync):
//   blk 0        : threefry chain t in [0,1024) -> keybuf; kmid -> XR_KMID
//   blk 1        : Riccati (tol cutoff) -> K10/Pp10/L10/tc (ws) + Mbuf/ebuf (xr)
//   blk 2..2049  : encoder z_mu (t = blk-2) -> XR_ZMU
__global__ void __launch_bounds__(256) svae_kA(
    const float* __restrict__ x,
    const float* __restrict__ ew1, const float* __restrict__ eb1,
    const float* __restrict__ ewx, const float* __restrict__ ebx,
    const float* __restrict__ A, const float* __restrict__ bvec,
    const float* __restrict__ Q, const int* __restrict__ seedp,
    float* __restrict__ xr, float* __restrict__ wsf) {
  int blk = blockIdx.x;

  if (blk == 0) {
    if (threadIdx.x != 0) return;
    unsigned long long us = (unsigned long long)(long long)(*seedp);
    unsigned k0 = (unsigned)(us >> 32), k1 = (unsigned)(us & 0xFFFFFFFFull);
    uint2* keys = (uint2*)(xr + XR_KEYS);
    bool ok = valu_selfcheck(k0, k1);
    if (ok) {
#pragma unroll 4
      for (int t = 0; t < T_LEN/2; ++t) {
        keys[t] = make_uint2(k0, k1);
        chain_step_valu(k0, k1);
      }
    } else {
      for (int t = 0; t < T_LEN/2; ++t) {
        keys[t] = make_uint2(k0, k1);
        unsigned t0 = 0u, t1 = 0u;
        tf_block(k0, k1, t0, t1);
        k0 = t0; k1 = t1;
      }
    }
    *(uint2*)(xr + XR_KMID) = make_uint2(k0, k1);
    return;
  }

  if (blk == 1) {
    // ---------------- Riccati chain (batch-independent) ----------------
    if (threadIdx.x != 0) return;
    float Am[16], Qm[16];
#pragma unroll
    for (int i = 0; i < 16; ++i) Am[i] = A[i];
    float bv[4];
#pragma unroll
    for (int i = 0; i < 4; ++i) bv[i] = bvec[i];
#pragma unroll
    for (int i = 0; i < 4; ++i)
#pragma unroll
      for (int j = 0; j < 4; ++j) {
        float s = 0.f;
#pragma unroll
        for (int k = 0; k < 4; ++k) s += Q[k*4+i] * Q[k*4+j];
        Qm[i*4+j] = s;
      }
    float P[16] = {1,0,0,0, 0,1,0,0, 0,0,1,0, 0,0,0,1};
    unsigned pb1[10], pb2[10];
    float pk[10];
#pragma unroll
    for (int i = 0; i < 10; ++i) { pb1[i] = 0xDEADBEEFu; pb2[i] = 0xFEEDFACEu; pk[i] = 1e30f; }
    int tc = T_LEN - 1;
    int streak = 0;
    float* K10  = wsf + WS_K10;
    float* Pp10 = wsf + WS_PP10;
    float* L10  = wsf + WS_L10;
    float* Mb   = xr + XR_MBUF;
    float* Eb   = xr + XR_EBUF;
    for (int t = 0; t < T_LEN; ++t) {
      float M[16];
#pragma unroll
      for (int i = 0; i < 4; ++i)
#pragma unroll
        for (int l = 0; l < 4; ++l) {
          float s = Am[i*4+0]*P[0*4+l];
          s += Am[i*4+1]*P[1*4+l];
          s += Am[i*4+2]*P[2*4+l];
          s += Am[i*4+3]*P[3*4+l];
          M[i*4+l] = s;
        }
      float Pp[16];
#pragma unroll
      for (int i = 0; i < 4; ++i)
#pragma unroll
        for (int j = 0; j < 4; ++j) {
          if (j > i) continue;
          float s = Qm[i*4+j];
          s += M[i*4+0]*Am[j*4+0];
          s += M[i*4+1]*Am[j*4+1];
          s += M[i*4+2]*Am[j*4+2];
          s += M[i*4+3]*Am[j*4+3];
          Pp[i*4+j] = s; Pp[j*4+i] = s;
        }
      float l00 = sqrtf(Pp[0]+1.f); float i00 = 1.f/l00;
      float l10 = Pp[4]*i00, l20 = Pp[8]*i00, l30 = Pp[12]*i00;
      float l11 = sqrtf(Pp[5]+1.f - l10*l10); float i11 = 1.f/l11;
      float l21 = (Pp[9]  - l20*l10)*i11;
      float l31 = (Pp[13] - l30*l10)*i11;
      float l22 = sqrtf(Pp[10]+1.f - l20*l20 - l21*l21); float i22 = 1.f/l22;
      float l32 = (Pp[14] - l30*l20 - l31*l21)*i22;
      float l33 = sqrtf(Pp[15]+1.f - l30*l30 - l31*l31 - l32*l32); float i33 = 1.f/l33;
      float Li10 = -(l10*i00)*i11;
      float Li20 = -(l20*i00 + l21*Li10)*i22;
      float Li21 = -(l21*i11)*i22;
      float Li30 = -(l30*i00 + l31*Li10 + l32*Li20)*i33;
      float Li31 = -(l31*i11 + l32*Li21)*i33;
      float Li32 = -(l32*i22)*i33;
      float Si00 = i00*i00 + Li10*Li10 + Li20*Li20 + Li30*Li30;
      float Si10 = Li10*i11 + Li20*Li21 + Li30*Li31;
      float Si11 = i11*i11 + Li21*Li21 + Li31*Li31;
      float Si20 = Li20*i22 + Li30*Li32;
      float Si21 = Li21*i22 + Li31*Li32;
      float Si22 = i22*i22 + Li32*Li32;
      float Si30 = Li30*i33;
      float Si31 = Li31*i33;
      float Si32 = Li32*i33;
      float Si33 = i33*i33;
      float Kv[10];
      Kv[0] = 1.f - Si00; Kv[1] = -Si10; Kv[2] = 1.f - Si11;
      Kv[3] = -Si20; Kv[4] = -Si21; Kv[5] = 1.f - Si22;
      Kv[6] = -Si30; Kv[7] = -Si31; Kv[8] = -Si32; Kv[9] = 1.f - Si33;
      float c00 = sqrtf(Kv[0]+1e-3f); float j00 = 1.f/c00;
      float c10 = Kv[1]*j00, c20 = Kv[3]*j00, c30 = Kv[6]*j00;
      float c11 = sqrtf(Kv[2]+1e-3f - c10*c10); float j11 = 1.f/c11;
      float c21 = (Kv[4] - c20*c10)*j11;
      float c31 = (Kv[7] - c30*c10)*j11;
      float c22 = sqrtf(Kv[5]+1e-3f - c20*c20 - c21*c21); float j22 = 1.f/c22;
      float c32 = (Kv[8] - c30*c20 - c31*c21)*j22;
      float c33 = sqrtf(Kv[9]+1e-3f - c30*c30 - c31*c31 - c32*c32);
      {
        float* kw = K10 + t*10;
#pragma unroll
        for (int i = 0; i < 10; ++i) kw[i] = Kv[i];
        float* pw = Pp10 + t*10;
        pw[0]=Pp[0]; pw[1]=Pp[4]; pw[2]=Pp[5]; pw[3]=Pp[8]; pw[4]=Pp[9];
        pw[5]=Pp[10]; pw[6]=Pp[12]; pw[7]=Pp[13]; pw[8]=Pp[14]; pw[9]=Pp[15];
        float* lw = L10 + t*10;
        lw[0]=c00; lw[1]=c10; lw[2]=c11; lw[3]=c20; lw[4]=c21;
        lw[5]=c22; lw[6]=c30; lw[7]=c31; lw[8]=c32; lw[9]=c33;
        float Kf[16] = {Kv[0],Kv[1],Kv[3],Kv[6],
                        Kv[1],Kv[2],Kv[4],Kv[7],
                        Kv[3],Kv[4],Kv[5],Kv[8],
                        Kv[6],Kv[7],Kv[8],Kv[9]};
        float* mw = Mb + t*16;
        float* ew = Eb + t*4;
#pragma unroll
        for (int j = 0; j < 4; ++j) {
          float g0 = (j==0?1.f:0.f) - Kf[j*4+0];
          float g1 = (j==1?1.f:0.f) - Kf[j*4+1];
          float g2 = (j==2?1.f:0.f) - Kf[j*4+2];
          float g3 = (j==3?1.f:0.f) - Kf[j*4+3];
#pragma unroll
          for (int i = 0; i < 4; ++i)
            mw[j*4+i] = g0*Am[i*4+0] + g1*Am[i*4+1] + g2*Am[i*4+2] + g3*Am[i*4+3];
          ew[j] = g0*bv[0] + g1*bv[1] + g2*bv[2] + g3*bv[3];
        }
      }
      unsigned nb[10];
#pragma unroll
      for (int i = 0; i < 10; ++i) nb[i] = __float_as_uint(Kv[i]);
      bool eq1 = true, eq2 = true;
      float dmax = 0.f;
#pragma unroll
      for (int i = 0; i < 10; ++i) {
        eq1 &= (nb[i]==pb1[i]); eq2 &= (nb[i]==pb2[i]);
        dmax = fmaxf(dmax, fabsf(Kv[i] - pk[i]));
      }
      streak = (dmax <= 1e-6f) ? (streak + 1) : 0;
      if (eq1 || eq2 || streak >= 2) { tc = t; break; }
#pragma unroll
      for (int i = 0; i < 10; ++i) { pb2[i] = pb1[i]; pb1[i] = nb[i]; pk[i] = Kv[i]; }
      P[0]=Kv[0];  P[1]=Kv[1];  P[2]=Kv[3];  P[3]=Kv[6];
      P[4]=Kv[1];  P[5]=Kv[2];  P[6]=Kv[4];  P[7]=Kv[7];
      P[8]=Kv[3];  P[9]=Kv[4];  P[10]=Kv[5]; P[11]=Kv[8];
      P[12]=Kv[6]; P[13]=Kv[7]; P[14]=Kv[8]; P[15]=Kv[9];
    }
    *((int*)(wsf + WS_TCONV)) = tc;
    return;
  }

  // ---------------- encoder: block = one t, 256 b's ----------------
  {
    int t = blk - 2;
    int b = threadIdx.x;
    float* zmu = xr + XR_ZMU;
    const float* xp = x + ((size_t)b * T_LEN + t) * NOBS;
    float xv[10];
#pragma unroll
    for (int i = 0; i < 10; ++i) xv[i] = xp[i];
    float h[6];
#pragma unroll
    for (int k = 0; k < 6; ++k) {
      float s = eb1[k];
#pragma unroll
      for (int i = 0; i < 10; ++i) s += xv[i]*ew1[i*6+k];
      h[k] = fmaxf(s, 0.f);
    }
    float z[4];
#pragma unroll
    for (int j = 0; j < 4; ++j) {
      float s = ebx[j];
#pragma unroll
      for (int k = 0; k < 6; ++k) s += h[k]*ewx[k*4+j];
      z[j] = s;
    }
    *reinterpret_cast<float4*>(zmu + (size_t)(t*BSZ + b)*4) =
        make_float4(z[0], z[1], z[2], z[3]);
  }
}

// Kernel B (grid 2177):
//   blk 0          : threefry chain t in [1024,2048) from kmid -> keybuf
//   blk 1..128     : phaseA chunk fold (c = blk-1) -> Vbuf, wbuf
//   blk 129..2176  : cov broadcast (t = blk-129) -> q_cov, p_cov
__global__ void __launch_bounds__(256) svae_kB(
    const int* __restrict__ seedp,
    float* __restrict__ xr, const float* __restrict__ wsc,
    float* __restrict__ q_cov, float* __restrict__ p_cov) {
  int blk = blockIdx.x;
  if (blk == 0) {
    if (threadIdx.x != 0) return;
    unsigned long long us = (unsigned long long)(long long)(*seedp);
    bool ok = valu_selfcheck((unsigned)(us >> 32), (unsigned)(us & 0xFFFFFFFFull));
    uint2 km = *(const uint2*)(xr + XR_KMID);
    unsigned k0 = km.x, k1 = km.y;
    uint2* keys = (uint2*)(xr + XR_KEYS);
    if (ok) {
#pragma unroll 4
      for (int t = T_LEN/2; t < T_LEN; ++t) {
        keys[t] = make_uint2(k0, k1);
        chain_step_valu(k0, k1);
      }
    } else {
      for (int t = T_LEN/2; t < T_LEN; ++t) {
        keys[t] = make_uint2(k0, k1);
        unsigned t0 = 0u, t1 = 0u;
        tf_block(k0, k1, t0, t1);
        k0 = t0; k1 = t1;
      }
    }
    return;
  }
  if (blk <= NCH) {
    // ---------------- phaseA: chunk-local affine fold ----------------
    int c = blk - 1;
    int b = threadIdx.x;
    const float* Mb  = xr + XR_MBUF;
    const float* Eb  = xr + XR_EBUF;
    const float* K10 = wsc + WS_K10;
    const float* zmu = xr + XR_ZMU;
    int tc = *((const int*)(wsc + WS_TCONV));
    float V[16] = {1,0,0,0, 0,1,0,0, 0,0,1,0, 0,0,0,1};
    float w0 = 0.f, w1 = 0.f, w2 = 0.f, w3 = 0.f;
#pragma unroll
    for (int k = 0; k < CHL; ++k) {
      int t = c*CHL + k;
      int tt = (t < tc) ? t : tc;
      const float* mp = Mb + (size_t)tt*16;
      const float* ep = Eb + (size_t)tt*4;
      const float* kp = K10 + (size_t)tt*10;
      float4 z = *reinterpret_cast<const float4*>(zmu + (size_t)(t*BSZ + b)*4);
      float k0=kp[0],k1=kp[1],k2=kp[2],k3=kp[3],k4=kp[4];
      float k5=kp[5],k6=kp[6],k7=kp[7],k8=kp[8],k9=kp[9];
      float c0 = ep[0] + k0*z.x + k1*z.y + k3*z.z + k6*z.w;
      float c1 = ep[1] + k1*z.x + k2*z.y + k4*z.z + k7*z.w;
      float c2 = ep[2] + k3*z.x + k4*z.y + k5*z.z + k8*z.w;
      float c3 = ep[3] + k6*z.x + k7*z.y + k8*z.z + k9*z.w;
      float m[16];
#pragma unroll
      for (int i = 0; i < 16; ++i) m[i] = mp[i];
      float nw0 = c0 + m[0]*w0 + m[1]*w1 + m[2]*w2 + m[3]*w3;
      float nw1 = c1 + m[4]*w0 + m[5]*w1 + m[6]*w2 + m[7]*w3;
      float nw2 = c2 + m[8]*w0 + m[9]*w1 + m[10]*w2 + m[11]*w3;
      float nw3 = c3 + m[12]*w0 + m[13]*w1 + m[14]*w2 + m[15]*w3;
      w0 = nw0; w1 = nw1; w2 = nw2; w3 = nw3;
      float nV[16];
#pragma unroll
      for (int j = 0; j < 4; ++j)
#pragma unroll
        for (int i = 0; i < 4; ++i)
          nV[j*4+i] = m[j*4+0]*V[0*4+i] + m[j*4+1]*V[1*4+i]
                    + m[j*4+2]*V[2*4+i] + m[j*4+3]*V[3*4+i];
#pragma unroll
      for (int i = 0; i < 16; ++i) V[i] = nV[i];
    }
    float* wb = xr + XR_WBUF;
    *reinterpret_cast<float4*>(wb + (size_t)(c*BSZ + b)*4) =
        make_float4(w0, w1, w2, w3);
    if (threadIdx.x == 0) {
      float* vb = xr + XR_VBUF + (size_t)c*16;
#pragma unroll
      for (int i = 0; i < 16; ++i) vb[i] = V[i];
    }
    return;
  }
  // ---------------- cov broadcast ----------------
  {
    int t = blk - (NCH + 1);
    int b = threadIdx.x;
    int tc = *((const int*)(wsc + WS_TCONV));
    int tt = (t < tc) ? t : tc;
    const float* kp = wsc + WS_K10 + (size_t)tt*10;
    const float* pp = wsc + WS_PP10 + (size_t)tt*10;
    float kv[10], pv[10];
#pragma unroll
    for (int i = 0; i < 10; ++i) { kv[i] = kp[i]; pv[i] = pp[i]; }
    float* qc = q_cov + (size_t)(t*BSZ + b)*16;
    float* pc = p_cov + (size_t)(t*BSZ + b)*16;
    const int mp[16] = {0,1,3,6, 1,2,4,7, 3,4,5,8, 6,7,8,9};
#pragma unroll
    for (int r = 0; r < 4; ++r) {
      *reinterpret_cast<float4*>(qc + r*4) = make_float4(
          kv[mp[r*4]], kv[mp[r*4+1]], kv[mp[r*4+2]], kv[mp[r*4+3]]);
      *reinterpret_cast<float4*>(pc + r*4) = make_float4(
          pv[mp[r*4]], pv[mp[r*4+1]], pv[mp[r*4+2]], pv[mp[r*4+3]]);
    }
  }
}

// Kernel D (grid 136):
//   blk 0..127   : chunk c -- redundant in-register boundary scan over chunks
//                  < c (V,w from phaseA), then exact 16-step recompute -> q_mu,p_mu
//   blk 128..135 : u-gen (t = (blk-128)*256 + tid) -> s4
__global__ void __launch_bounds__(256) svae_kD(
    const float* __restrict__ A, const float* __restrict__ bvec,
    const float* __restrict__ xr, const float* __restrict__ wsc,
    float* __restrict__ wsf,
    float* __restrict__ q_mu, float* __restrict__ p_mu) {
  int blk = blockIdx.x;
  if (blk < NCH) {
    int c = blk;
    int b = threadIdx.x;
    const float* vb = xr + XR_VBUF;
    const float* wb = xr + XR_WBUF;
    float mu0 = 0.f, mu1 = 0.f, mu2 = 0.f, mu3 = 0.f;
    for (int cc = 0; cc < c; ++cc) {
      const float* V = vb + (size_t)cc*16;
      float4 wv = *reinterpret_cast<const float4*>(wb + (size_t)(cc*BSZ + b)*4);
      float n0 = wv.x + V[0]*mu0  + V[1]*mu1  + V[2]*mu2  + V[3]*mu3;
      float n1 = wv.y + V[4]*mu0  + V[5]*mu1  + V[6]*mu2  + V[7]*mu3;
      float n2 = wv.z + V[8]*mu0  + V[9]*mu1  + V[10]*mu2 + V[11]*mu3;
      float n3 = wv.w + V[12]*mu0 + V[13]*mu1 + V[14]*mu2 + V[15]*mu3;
      mu0 = n0; mu1 = n1; mu2 = n2; mu3 = n3;
    }
    const float* K10 = wsc + WS_K10;
    const float* zmu = xr + XR_ZMU;
    int tc = *((const int*)(wsc + WS_TCONV));
    float Am[16];
#pragma unroll
    for (int i = 0; i < 16; ++i) Am[i] = A[i];
    float b0 = bvec[0], b1 = bvec[1], b2 = bvec[2], b3 = bvec[3];
#pragma unroll
    for (int k = 0; k < CHL; ++k) {
      int t = c*CHL + k;
      int tt = (t < tc) ? t : tc;
      const float* kp = K10 + (size_t)tt*10;
      float kc0=kp[0],kc1=kp[1],kc2=kp[2],kc3=kp[3],kc4=kp[4];
      float kc5=kp[5],kc6=kp[6],kc7=kp[7],kc8=kp[8],kc9=kp[9];
      float4 zv = *reinterpret_cast<const float4*>(zmu + (size_t)(t*BSZ + b)*4);
      float mp0 = b0 + mu0*Am[0] + mu1*Am[4] + mu2*Am[8]  + mu3*Am[12];
      float mp1 = b1 + mu0*Am[1] + mu1*Am[5] + mu2*Am[9]  + mu3*Am[13];
      float mp2 = b2 + mu0*Am[2] + mu1*Am[6] + mu2*Am[10] + mu3*Am[14];
      float mp3 = b3 + mu0*Am[3] + mu1*Am[7] + mu2*Am[11] + mu3*Am[15];
      float r0 = zv.x - mp0, r1 = zv.y - mp1, r2 = zv.z - mp2, r3 = zv.w - mp3;
      mu0 = mp0 + kc0*r0 + kc1*r1 + kc3*r2 + kc6*r3;
      mu1 = mp1 + kc1*r0 + kc2*r1 + kc4*r2 + kc7*r3;
      mu2 = mp2 + kc3*r0 + kc4*r1 + kc5*r2 + kc8*r3;
      mu3 = mp3 + kc6*r0 + kc7*r1 + kc8*r2 + kc9*r3;
      *reinterpret_cast<float4*>(p_mu + (size_t)(t*BSZ + b)*4) =
          make_float4(mp0, mp1, mp2, mp3);
      *reinterpret_cast<float4*>(q_mu + (size_t)(t*BSZ + b)*4) =
          make_float4(mu0, mu1, mu2, mu3);
    }
    return;
  }
  // ---------------- u-gen: 4 normals per t, s_t = u^T L ----------------
  {
    int t = (blk - NCH) * 256 + threadIdx.x;
    const uint2* keys = (const uint2*)(xr + XR_KEYS);
    const float* L10 = wsc + WS_L10;
    int tc = *((const int*)(wsc + WS_TCONV));
    const float LO = __uint_as_float(0xBF7FFFFFu);   // nextafter(-1,0)
    float* s4 = wsf + WS_S4;
    uint2 kk = keys[t];
    unsigned s0 = 0u, s1 = 1u;            // skey: ctr (0,1)
    tf_block(kk.x, kk.y, s0, s1);
    float n[4];
#pragma unroll
    for (int i = 0; i < 4; ++i) {
      unsigned y0 = 0u, y1 = (unsigned)i;  // bits: ctr (0,i), fold xor
      tf_block(s0, s1, y0, y1);
      unsigned bits = y0 ^ y1;
      float f = __uint_as_float((bits >> 9) | 0x3F800000u) - 1.0f;
      float v = fmaxf(LO, f * 2.0f + LO);
      n[i] = 1.41421356237309505f * erfinv_xla(v);
    }
    const float* Lp = L10 + (size_t)((t < tc) ? t : tc) * 10;
    float s_0 = n[0]*Lp[0] + n[1]*Lp[1] + n[2]*Lp[3] + n[3]*Lp[6];
    float s_1 = n[1]*Lp[2] + n[2]*Lp[4] + n[3]*Lp[7];
    float s_2 = n[2]*Lp[5] + n[3]*Lp[8];
    float s_3 = n[3]*Lp[9];
    *reinterpret_cast<float4*>(s4 + 4*t) = make_float4(s_0, s_1, s_2, s_3);
  }
}

// Kernel E (grid 256): decoder, block = batch b, threads over t (contiguous
// 40B stores per lane). Overwrites all xr scratch -- must be LAST.
__global__ void __launch_bounds__(256) svae_kE(
    const float* __restrict__ q_mu, const float* __restrict__ wsc,
    const float* __restrict__ dw1, const float* __restrict__ db1,
    const float* __restrict__ dw2, const float* __restrict__ db2,
    float* __restrict__ xr) {
  int b = blockIdx.x;
  const float* s4 = wsc + WS_S4;
  float w1[24], bb1[6], w2[60], bb2[10];
#pragma unroll
  for (int i = 0; i < 24; ++i) w1[i] = dw1[i];
#pragma unroll
  for (int i = 0; i < 6; ++i) bb1[i] = db1[i];
#pragma unroll
  for (int i = 0; i < 60; ++i) w2[i] = dw2[i];
#pragma unroll
  for (int i = 0; i < 10; ++i) bb2[i] = db2[i];
#pragma unroll
  for (int i = 0; i < T_LEN / 256; ++i) {
    int t = i * 256 + threadIdx.x;
    float4 mu = *reinterpret_cast<const float4*>(q_mu + (size_t)(t*BSZ + b)*4);
    float4 sv = *reinterpret_cast<const float4*>(s4 + 4*t);
    float z0 = mu.x + sv.x, z1 = mu.y + sv.y, z2 = mu.z + sv.z, z3 = mu.w + sv.w;
    float hd[6];
#pragma unroll
    for (int k = 0; k < 6; ++k) {
      float v = bb1[k] + z0*w1[k] + z1*w1[6+k] + z2*w1[12+k] + z3*w1[18+k];
      hd[k] = fmaxf(v, 0.f);
    }
    float o[10];
#pragma unroll
    for (int oo = 0; oo < 10; ++oo) {
      float v = bb2[oo];
#pragma unroll
      for (int k = 0; k < 6; ++k) v += hd[k]*w2[k*10+oo];
      o[oo] = v;
    }
    float* xo = xr + ((size_t)b * T_LEN + t) * 10;
#pragma unroll
    for (int p2 = 0; p2 < 5; ++p2)
      *reinterpret_cast<float2*>(xo + p2*2) = make_float2(o[p2*2], o[p2*2+1]);
  }
}

extern "C" void kernel_launch(void* const* d_in, const int* in_sizes, int n_in,
                              void* d_out, int out_size, void* d_ws, size_t ws_size,
                              hipStream_t stream) {
  const float* x   = (const float*)d_in[0];
  const float* ew1 = (const float*)d_in[1];
  const float* eb1 = (const float*)d_in[2];
  const float* ewx = (const float*)d_in[3];
  const float* ebx = (const float*)d_in[4];
  // d_in[5], d_in[6]: enc_wl/enc_bl -- unused by the filter
  const float* dw1 = (const float*)d_in[7];
  const float* db1 = (const float*)d_in[8];
  const float* dw2 = (const float*)d_in[9];
  const float* db2 = (const float*)d_in[10];
  const float* Ain = (const float*)d_in[11];
  const float* bin = (const float*)d_in[12];
  const float* Qin = (const float*)d_in[13];
  const int* seed  = (const int*)d_in[14];

  float* out   = (float*)d_out;
  float* xr    = out + OFF_XR;     // also hosts all large scratch until kE
  float* q_mu  = out + OFF_QMU;
  float* q_cov = out + OFF_QCOV;
  float* p_mu  = out + OFF_PMU;
  float* p_cov = out + OFF_PCOV;
  float* wsf   = (float*)d_ws;

  svae_kA<<<T_LEN + 2, 256, 0, stream>>>(x, ew1, eb1, ewx, ebx, Ain, bin, Qin,
                                         seed, xr, wsf);
  svae_kB<<<1 + NCH + T_LEN, 256, 0, stream>>>(seed, xr, wsf, q_cov, p_cov);
  svae_kD<<<NCH + 8, 256, 0, stream>>>(Ain, bin, xr, wsf, wsf, q_mu, p_mu);
  svae_kE<<<BSZ, 256, 0, stream>>>(q_mu, wsf, dw1, db1, dw2, db2, xr);
}